// Round 6
// baseline (440.239 us; speedup 1.0000x reference)
//
#include <hip/hip_runtime.h>
#include <hip/hip_bf16.h>

// Problem constants (fixed by the reference)
#define N_NODES 10000
#define N_EDGES 160000
#define ETOT    (N_NODES + N_EDGES)
#define DIM     1024
#define NHEAD   4
#define DHEAD   256
#define NGRAPH  64
#define NEG_SLOPE 0.2f

typedef short  bf16x8 __attribute__((ext_vector_type(8)));
typedef float  f32x4  __attribute__((ext_vector_type(4)));
typedef unsigned short u16x4 __attribute__((ext_vector_type(4)));
typedef unsigned short u16x8 __attribute__((ext_vector_type(8)));

__device__ __forceinline__ unsigned short f2bf_rne(float v) {
    unsigned u = __builtin_bit_cast(unsigned, v);
    return (unsigned short)((u + 0x7fffu + ((u >> 16) & 1u)) >> 16);
}
__device__ __forceinline__ float bf2f(unsigned short b) {
    return __builtin_bit_cast(float, (unsigned)b << 16);
}
__device__ __forceinline__ float lrelu(float x) { return x > 0.f ? x : NEG_SLOPE * x; }

// ---------------- split x into bf16 hi/lo ----------------
__global__ __launch_bounds__(256) void prep_x(const float* __restrict__ x,
                                              unsigned short* __restrict__ xhi,
                                              unsigned short* __restrict__ xlo) {
    int i = blockIdx.x * 256 + threadIdx.x;     // group of 4 floats
    if ((size_t)i * 4 >= (size_t)N_NODES * DIM) return;
    f32x4 v = *(const f32x4*)(x + (size_t)i * 4);
    u16x4 hi, lo;
#pragma unroll
    for (int j = 0; j < 4; ++j) {
        unsigned short hb = f2bf_rne(v[j]);
        float r = v[j] - bf2f(hb);
        hi[j] = hb;
        lo[j] = f2bf_rne(r);
    }
    *(u16x4*)(xhi + (size_t)i * 4) = hi;
    *(u16x4*)(xlo + (size_t)i * 4) = lo;
}

// ---------------- transpose + split W[2] -> Wt (col-major K-contig) ----------------
__global__ __launch_bounds__(256) void prep_w(const float* __restrict__ W2,
                                              unsigned short* __restrict__ wthi,
                                              unsigned short* __restrict__ wtlo) {
    __shared__ float tile[64][65];
    int bc = blockIdx.x;      // output-col tile
    int bk = blockIdx.y;      // k tile
    int t = threadIdx.x;
    int tj = t & 63, ti = t >> 6;
#pragma unroll
    for (int u = 0; u < 16; ++u) {
        int r = u * 4 + ti;   // k-local
        tile[r][tj] = W2[(size_t)(bk * 64 + r) * DIM + bc * 64 + tj];
    }
    __syncthreads();
#pragma unroll
    for (int u = 0; u < 16; ++u) {
        int cr = u * 4 + ti;  // c-local
        float v = tile[tj][cr];   // = W2[bk*64+tj][bc*64+cr]
        unsigned short hb = f2bf_rne(v);
        float rres = v - bf2f(hb);
        size_t o = (size_t)(bc * 64 + cr) * DIM + bk * 64 + tj;
        wthi[o] = hb;
        wtlo[o] = f2bf_rne(rres);
    }
}

// ---------------- 3-term split-bf16 MFMA GEMM: h = x @ W2 (bf16 output) ----------------
// x @ W ~= xhi@Whi + xhi@Wlo + xlo@Whi  (fp32 accumulate)
//
// LDS is stored in MFMA FRAGMENT ORDER: subtile s (16 rows x 32 k) occupies
// [s*1024, (s+1)*1024) bytes with lane l's fragment at s*1024 + l*16.
//   element (row, k) -> s=row>>4: byte = s*1024 + ((k>>3)*16 + (row&15))*16 + (k&7)*2
// Fragment ds_read_b128: addr = base + lane*16 -> linear 1 KB, ZERO bank
// conflicts. (Round-5 layout row*BK+koff had lanes at stride 64 B -> 8-way
// conflict, SQ_LDS_BANK_CONFLICT=5.18M.) Per rule #21, the global SOURCE lane
// mapping is permuted to match the linear LDS dest of global_load_lds.
#define BM 128
#define BN 128
#define BK 32
#define NROWT ((N_NODES + BM - 1) / BM)   // 79 row tiles
#define NCOLT (DIM / BN)                  // 8 col tiles

__global__ __launch_bounds__(256) void gemm3(const unsigned short* __restrict__ xhi,
                                             const unsigned short* __restrict__ xlo,
                                             const unsigned short* __restrict__ wthi,
                                             const unsigned short* __restrict__ wtlo,
                                             unsigned short* __restrict__ hb) {
    // XCD-grouping swizzle: assuming round-robin id%8 -> XCD, the 8 col-tiles
    // sharing one A row-block run consecutively on ONE XCD (A stays in its L2).
    const int id = blockIdx.x;
    const int xcd = id & 7;
    const int br = xcd + 8 * (id >> 6);     // row tile
    const int bc = (id >> 3) & 7;           // col tile
    if (br >= NROWT) return;
    const int r0 = br * BM;
    const int c0 = bc * BN;

    __shared__ short lds[4][BM * BK];   // 0:Ahi 1:Alo 2:Bhi 3:Blo — 8 KB each
    const int t = threadIdx.x;
    const int lane = t & 63, wid = t >> 6;
    const int wm = wid >> 1, wn = wid & 1;

    // each wave stages its own buffer: wave 0:Ahi 1:Alo 2:Bhi 3:Blo
    const unsigned short* const srcs[4] = {xhi, xlo, wthi, wtlo};
    const unsigned short* wbase = srcs[wid];
    const int rowb = (wid < 2) ? r0 : c0;
    // OOB A-rows (r0+row >= N_NODES) read garbage inside ws; those acc lanes are
    // never stored (row<N_NODES guard).

    f32x4 acc[4][4];
#pragma unroll
    for (int mi = 0; mi < 4; ++mi)
#pragma unroll
        for (int ni = 0; ni < 4; ++ni) acc[mi][ni] = (f32x4){0.f, 0.f, 0.f, 0.f};

    for (int k0 = 0; k0 < DIM; k0 += BK) {
        __syncthreads();   // previous iteration's fragment reads done before overwrite
#pragma unroll
        for (int j = 0; j < 8; ++j) {
            // subtile j: lane i loads (row j*16 + (i&15), k k0 + (i>>4)*8 .. +7)
            // -> lands at lds[wid][j*512 + i*8] (global_load_lds linear dest).
            // Coalescing: lanes {i,i+16,i+32,i+48} cover 64 contiguous bytes.
            const unsigned short* g = wbase
                + (size_t)(rowb + j * 16 + (lane & 15)) * DIM + k0 + (lane >> 4) * 8;
            __builtin_amdgcn_global_load_lds(
                (const __attribute__((address_space(1))) unsigned int*)g,
                (__attribute__((address_space(3))) unsigned int*)&lds[wid][j * 512],
                16, 0, 0);
        }
        __syncthreads();   // compiler drains vmcnt before barrier

        bf16x8 ahi[4], alo[4], bhi[4], blo[4];
#pragma unroll
        for (int mi = 0; mi < 4; ++mi) {
            int sub = wm * 4 + mi;          // A subtile index (row>>4)
            ahi[mi] = *(const bf16x8*)&lds[0][sub * 512 + lane * 8];
            alo[mi] = *(const bf16x8*)&lds[1][sub * 512 + lane * 8];
        }
#pragma unroll
        for (int ni = 0; ni < 4; ++ni) {
            int sub = wn * 4 + ni;          // B subtile index
            bhi[ni] = *(const bf16x8*)&lds[2][sub * 512 + lane * 8];
            blo[ni] = *(const bf16x8*)&lds[3][sub * 512 + lane * 8];
        }
#pragma unroll
        for (int mi = 0; mi < 4; ++mi)
#pragma unroll
            for (int ni = 0; ni < 4; ++ni) {
                f32x4 c = acc[mi][ni];
                c = __builtin_amdgcn_mfma_f32_16x16x32_bf16(ahi[mi], bhi[ni], c, 0, 0, 0);
                c = __builtin_amdgcn_mfma_f32_16x16x32_bf16(ahi[mi], blo[ni], c, 0, 0, 0);
                c = __builtin_amdgcn_mfma_f32_16x16x32_bf16(alo[mi], bhi[ni], c, 0, 0, 0);
                acc[mi][ni] = c;
            }
    }

    // epilogue: bf16 store (C/D map: col=lane&15, row=(lane>>4)*4+v  [m89/m91])
#pragma unroll
    for (int mi = 0; mi < 4; ++mi)
#pragma unroll
        for (int ni = 0; ni < 4; ++ni)
#pragma unroll
            for (int v = 0; v < 4; ++v) {
                int row = r0 + wm * 64 + mi * 16 + ((lane >> 4) << 2) + v;
                if (row < N_NODES) {
                    int col = c0 + wn * 64 + ni * 16 + (lane & 15);
                    hb[(size_t)row * DIM + col] = f2bf_rne(acc[mi][ni][v]);
                }
            }
}

// ---------------- per-node attention logits es/ed (bf16 h, vectorized) ----------------
__global__ __launch_bounds__(256) void dots_k(const unsigned short* __restrict__ hb,
                                              const float* __restrict__ asrc,
                                              const float* __restrict__ adst,
                                              float* __restrict__ es,
                                              float* __restrict__ ed) {
    int wid = threadIdx.x >> 6, lane = threadIdx.x & 63;
    int n = blockIdx.x * 4 + wid;
    if (n >= N_NODES) return;
    // lane owns elements [lane*16, lane*16+16) -> all within head lane>>4
    const unsigned short* hr = hb + (size_t)n * DIM + lane * 16;
    u16x8 a = *(const u16x8*)hr;
    u16x8 b8 = *(const u16x8*)(hr + 8);
    const float* ap = asrc + lane * 16;
    const float* dp = adst + lane * 16;
    float sa = 0.f, sd = 0.f;
#pragma unroll
    for (int j = 0; j < 8; ++j) {
        float v = bf2f(a[j]);
        sa += v * ap[j];
        sd += v * dp[j];
    }
#pragma unroll
    for (int j = 0; j < 8; ++j) {
        float v = bf2f(b8[j]);
        sa += v * ap[8 + j];
        sd += v * dp[8 + j];
    }
#pragma unroll
    for (int d = 1; d < 16; d <<= 1) {
        sa += __shfl_xor(sa, d);
        sd += __shfl_xor(sd, d);
    }
    if ((lane & 15) == 0) {
        int head = lane >> 4;
        es[(size_t)n * 4 + head] = sa;
        ed[(size_t)n * 4 + head] = sd;
    }
}

// ---------------- per-graph init ----------------
__global__ void init_misc(int* gcnt, int* gbeg, int* gend) {
    int t = threadIdx.x;
    if (t < NGRAPH) { gcnt[t] = 0; gbeg[t] = 0x7fffffff; gend[t] = -1; }
}

// ---------------- CSR build ----------------
__global__ void init_counts(const int* __restrict__ batch, int* cnt, int* cursor,
                            int* gcnt, int* gbeg, int* gend) {
    int n = blockIdx.x * 256 + threadIdx.x;
    if (n >= N_NODES) return;
    cnt[n] = 1;          // self loop
    cursor[n] = 0;
    int b = batch[n];
    atomicAdd(gcnt + b, 1);
    atomicMin(gbeg + b, n);
    atomicMax(gend + b, n);
}

__global__ void edge_hist(const int* __restrict__ dst, int* cnt) {
    int e = blockIdx.x * 256 + threadIdx.x;
    if (e >= N_EDGES) return;
    atomicAdd(cnt + dst[e], 1);
}

// shfl-based scan (wave-level, few barriers)
__global__ __launch_bounds__(1024) void scan_k(const int* __restrict__ cnt, int* __restrict__ off) {
    __shared__ int wsh[16];
    __shared__ int tot_s;
    int t = threadIdx.x, lane = t & 63, wv = t >> 6;
    int running = 0;
    for (int c0 = 0; c0 < N_NODES; c0 += 1024) {
        int i = c0 + t;
        int v = (i < N_NODES) ? cnt[i] : 0;
        int s = v;
#pragma unroll
        for (int d = 1; d < 64; d <<= 1) {
            int y = __shfl_up(s, d);
            if (lane >= d) s += y;
        }
        if (lane == 63) wsh[wv] = s;
        __syncthreads();
        if (wv == 0) {
            int wsv = (lane < 16) ? wsh[lane] : 0;
            int e = wsv;
#pragma unroll
            for (int d = 1; d < 16; d <<= 1) {
                int y = __shfl_up(e, d);
                if (lane >= d) e += y;
            }
            if (lane < 16) wsh[lane] = e - wsv;   // exclusive wave prefix
            if (lane == 15) tot_s = e;            // chunk total
        }
        __syncthreads();
        if (i < N_NODES) off[i] = running + wsh[wv] + s - v;
        running += tot_s;
    }
}

__global__ void bucket_k(const int* __restrict__ src, const int* __restrict__ dst,
                         const int* __restrict__ off, int* cursor, int* bucket) {
    int e = blockIdx.x * 256 + threadIdx.x;
    if (e >= ETOT) return;
    int d = (e < N_EDGES) ? dst[e] : (e - N_EDGES);
    int pos = atomicAdd(cursor + d, 1);
    bucket[off[d] + pos] = e;
}

// ---------------- fused softmax + aggregate + bias + relu -> out[n] ----------------
#define HCAP 192
__global__ __launch_bounds__(256) void aggregate_k(const unsigned short* __restrict__ hb,
                                                   const float* __restrict__ es,
                                                   const float* __restrict__ ed,
                                                   const int* __restrict__ src,
                                                   const int* __restrict__ cnt,
                                                   const int* __restrict__ off,
                                                   const int* __restrict__ bucket,
                                                   const float* __restrict__ b2,
                                                   float* __restrict__ out) {
    int n = blockIdx.x, t = threadIdx.x;
    int deg = cnt[n], base = off[n];
    f32x4 edn = *(const f32x4*)(ed + (size_t)n * 4);
    __shared__ int  s_src[HCAP];
    __shared__ f32x4 s_e[HCAP];
    __shared__ f32x4 wred[4];

    // phase 1: edge scores + per-head max
    f32x4 m4 = {-3e38f, -3e38f, -3e38f, -3e38f};
    for (int i = t; i < deg; i += 256) {
        int eid = bucket[base + i];
        int s = (eid < N_EDGES) ? src[eid] : (eid - N_EDGES);
        f32x4 e4 = *(const f32x4*)(es + (size_t)s * 4);
        e4.x = lrelu(e4.x + edn.x); e4.y = lrelu(e4.y + edn.y);
        e4.z = lrelu(e4.z + edn.z); e4.w = lrelu(e4.w + edn.w);
        if (i < HCAP) { s_src[i] = s; s_e[i] = e4; }
        m4.x = fmaxf(m4.x, e4.x); m4.y = fmaxf(m4.y, e4.y);
        m4.z = fmaxf(m4.z, e4.z); m4.w = fmaxf(m4.w, e4.w);
    }
#pragma unroll
    for (int d = 1; d < 64; d <<= 1) {
        m4.x = fmaxf(m4.x, __shfl_xor(m4.x, d));
        m4.y = fmaxf(m4.y, __shfl_xor(m4.y, d));
        m4.z = fmaxf(m4.z, __shfl_xor(m4.z, d));
        m4.w = fmaxf(m4.w, __shfl_xor(m4.w, d));
    }
    if ((t & 63) == 0) wred[t >> 6] = m4;
    __syncthreads();
    f32x4 mm = wred[0];
#pragma unroll
    for (int w = 1; w < 4; ++w) {
        mm.x = fmaxf(mm.x, wred[w].x); mm.y = fmaxf(mm.y, wred[w].y);
        mm.z = fmaxf(mm.z, wred[w].z); mm.w = fmaxf(mm.w, wred[w].w);
    }
    int hd = t >> 6;
    float mh = hd == 0 ? mm.x : hd == 1 ? mm.y : hd == 2 ? mm.z : mm.w;

    // phase 2: weighted accumulate over bf16 h rows (thread t owns cols [t*4, t*4+4))
    f32x4 acc = {0.f, 0.f, 0.f, 0.f};
    float sump = 0.f;
    for (int i = 0; i < deg; ++i) {
        int s;
        f32x4 e4;
        if (i < HCAP) { s = s_src[i]; e4 = s_e[i]; }
        else {
            int eid = bucket[base + i];
            s = (eid < N_EDGES) ? src[eid] : (eid - N_EDGES);
            e4 = *(const f32x4*)(es + (size_t)s * 4);
            e4.x = lrelu(e4.x + edn.x); e4.y = lrelu(e4.y + edn.y);
            e4.z = lrelu(e4.z + edn.z); e4.w = lrelu(e4.w + edn.w);
        }
        float eh = hd == 0 ? e4.x : hd == 1 ? e4.y : hd == 2 ? e4.z : e4.w;
        float p = expf(eh - mh);
        sump += p;
        u16x4 q = *(const u16x4*)(hb + (size_t)s * DIM + t * 4);
        f32x4 hv = {bf2f(q[0]), bf2f(q[1]), bf2f(q[2]), bf2f(q[3])};
        acc += p * hv;
    }
    float inv = 1.0f / (sump + 1e-16f);
    f32x4 bb = *(const f32x4*)(b2 + t * 4);
    f32x4 r = acc * inv + bb;
    r.x = fmaxf(r.x, 0.f); r.y = fmaxf(r.y, 0.f);
    r.z = fmaxf(r.z, 0.f); r.w = fmaxf(r.w, 0.f);
    *(f32x4*)(out + (size_t)n * DIM + t * 4) = r;   // plain coalesced store, no atomics
}

// ---------------- per-graph pooling (no atomics: batch is sorted) ----------------
__global__ __launch_bounds__(256) void pool_k(const float* __restrict__ out,
                                              const int* __restrict__ gbeg,
                                              const int* __restrict__ gend,
                                              float* __restrict__ pooled) {
    int g = blockIdx.x, c = blockIdx.y, t = threadIdx.x;
    int col = c * 256 + t;
    int b0 = gbeg[g], b1 = gend[g];
    float acc = 0.f;
    for (int n = b0; n <= b1; ++n) acc += out[(size_t)n * DIM + col];
    pooled[(size_t)g * DIM + col] = acc;   // sum; final_k divides by count
}

// ---------------- final: (pooled/cnt) @ Wr + br ----------------
__global__ __launch_bounds__(256) void final_k(const float* __restrict__ pooled,
                                               const int* __restrict__ gcnt,
                                               const float* __restrict__ Wr,
                                               const float* __restrict__ br,
                                               float* __restrict__ out) {
    int g = blockIdx.x, t = threadIdx.x;
    float s0 = 0.f, s1 = 0.f;
    for (int d = t; d < DIM; d += 256) {
        float v = pooled[(size_t)g * DIM + d];
        s0 += v * Wr[d * 2];
        s1 += v * Wr[d * 2 + 1];
    }
    __shared__ float r0[256], r1[256];
    r0[t] = s0; r1[t] = s1;
    __syncthreads();
    for (int st = 128; st > 0; st >>= 1) {
        if (t < st) { r0[t] += r0[t + st]; r1[t] += r1[t + st]; }
        __syncthreads();
    }
    if (t == 0) {
        float c = fmaxf((float)gcnt[g], 1.f);
        out[g * 2 + 0] = r0[0] / c + br[0];
        out[g * 2 + 1] = r1[0] / c + br[1];
    }
}

// ---------------- launch ----------------
extern "C" void kernel_launch(void* const* d_in, const int* in_sizes, int n_in,
                              void* d_out, int out_size, void* d_ws, size_t ws_size,
                              hipStream_t stream) {
    (void)in_sizes; (void)n_in; (void)out_size; (void)ws_size;
    const float* x     = (const float*)d_in[0];
    const int*   ei    = (const int*)d_in[1];
    const int*   batch = (const int*)d_in[2];
    const float* W     = (const float*)d_in[3];
    const float* a_src = (const float*)d_in[4];
    const float* a_dst = (const float*)d_in[5];
    const float* b     = (const float*)d_in[6];
    const float* Wr    = (const float*)d_in[7];
    const float* br    = (const float*)d_in[8];

    // Reference: each block reads the ORIGINAL x -> only block i=2 matters.
    const float* W2    = W + (size_t)2 * DIM * DIM;
    const float* asrc2 = a_src + 2 * NHEAD * DHEAD;
    const float* adst2 = a_dst + 2 * NHEAD * DHEAD;
    const float* b2    = b + 2 * DIM;
    const int* srcI = ei;
    const int* dstI = ei + N_EDGES;

    char* wsp = (char*)d_ws;
    size_t o = 0;
    auto alloc = [&](size_t bytes) -> char* {
        char* p = wsp + o;
        o = (o + bytes + 255) & ~(size_t)255;
        return p;
    };
    unsigned short* xhi  = (unsigned short*)alloc((size_t)N_NODES * DIM * 2);  // 20.48 MB
    unsigned short* xlo  = (unsigned short*)alloc((size_t)N_NODES * DIM * 2);  // 20.48 MB (contiguous after xhi)
    unsigned short* wthi = (unsigned short*)alloc((size_t)DIM * DIM * 2);
    unsigned short* wtlo = (unsigned short*)alloc((size_t)DIM * DIM * 2);
    unsigned short* hb   = (unsigned short*)alloc((size_t)N_NODES * DIM * 2);  // h in bf16
    float* es   = (float*)alloc((size_t)N_NODES * 4 * 4);
    float* ed   = (float*)alloc((size_t)N_NODES * 4 * 4);
    int*   cnt  = (int*)alloc((size_t)N_NODES * 4);
    int*   offs = (int*)alloc((size_t)N_NODES * 4);
    int*   curs = (int*)alloc((size_t)N_NODES * 4);
    int*   bkt  = (int*)alloc((size_t)ETOT * 4);
    float* pooled = (float*)alloc((size_t)NGRAPH * DIM * 4);
    int*   gcnt   = (int*)alloc(NGRAPH * 4);
    int*   gbeg   = (int*)alloc(NGRAPH * 4);
    int*   gend   = (int*)alloc(NGRAPH * 4);
    // out[n] (41 MB f32) aliases xhi+xlo — dead after gemm3. (xhi size is a
    // multiple of 256 so xlo is contiguous; combined = exactly N*DIM*4 bytes.)
    float* outn = (float*)xhi;

    init_misc<<<1, 64, 0, stream>>>(gcnt, gbeg, gend);
    prep_x<<<(N_NODES * DIM / 4 + 255) / 256, 256, 0, stream>>>(x, xhi, xlo);
    prep_w<<<dim3(16, 16), 256, 0, stream>>>(W2, wthi, wtlo);
    gemm3<<<((NROWT + 7) / 8) * 8 * NCOLT, 256, 0, stream>>>(xhi, xlo, wthi, wtlo, hb);
    dots_k<<<(N_NODES + 3) / 4, 256, 0, stream>>>(hb, asrc2, adst2, es, ed);

    init_counts<<<(N_NODES + 255) / 256, 256, 0, stream>>>(batch, cnt, curs, gcnt, gbeg, gend);
    edge_hist<<<(N_EDGES + 255) / 256, 256, 0, stream>>>(dstI, cnt);
    scan_k<<<1, 1024, 0, stream>>>(cnt, offs);
    bucket_k<<<(ETOT + 255) / 256, 256, 0, stream>>>(srcI, dstI, offs, curs, bkt);

    aggregate_k<<<N_NODES, 256, 0, stream>>>(hb, es, ed, srcI, cnt, offs, bkt, b2, outn);
    pool_k<<<dim3(NGRAPH, 4), 256, 0, stream>>>(outn, gbeg, gend, pooled);
    final_k<<<NGRAPH, 256, 0, stream>>>(pooled, gcnt, Wr, br, (float*)d_out);
}

// Round 7
// 404.280 us; speedup vs baseline: 1.0889x; 1.0889x over previous
//
#include <hip/hip_runtime.h>
#include <hip/hip_bf16.h>

// Problem constants (fixed by the reference)
#define N_NODES 10000
#define N_EDGES 160000
#define ETOT    (N_NODES + N_EDGES)
#define DIM     1024
#define NHEAD   4
#define DHEAD   256
#define NGRAPH  64
#define NEG_SLOPE 0.2f

typedef short  bf16x8 __attribute__((ext_vector_type(8)));
typedef float  f32x4  __attribute__((ext_vector_type(4)));
typedef unsigned short u16x4 __attribute__((ext_vector_type(4)));
typedef unsigned short u16x8 __attribute__((ext_vector_type(8)));

__device__ __forceinline__ unsigned short f2bf_rne(float v) {
    unsigned u = __builtin_bit_cast(unsigned, v);
    return (unsigned short)((u + 0x7fffu + ((u >> 16) & 1u)) >> 16);
}
__device__ __forceinline__ float bf2f(unsigned short b) {
    return __builtin_bit_cast(float, (unsigned)b << 16);
}
__device__ __forceinline__ float lrelu(float x) { return x > 0.f ? x : NEG_SLOPE * x; }

// ---------------- split x into bf16 hi/lo ----------------
__global__ __launch_bounds__(256) void prep_x(const float* __restrict__ x,
                                              unsigned short* __restrict__ xhi,
                                              unsigned short* __restrict__ xlo) {
    int i = blockIdx.x * 256 + threadIdx.x;     // group of 4 floats
    if ((size_t)i * 4 >= (size_t)N_NODES * DIM) return;
    f32x4 v = *(const f32x4*)(x + (size_t)i * 4);
    u16x4 hi, lo;
#pragma unroll
    for (int j = 0; j < 4; ++j) {
        unsigned short hb = f2bf_rne(v[j]);
        float r = v[j] - bf2f(hb);
        hi[j] = hb;
        lo[j] = f2bf_rne(r);
    }
    *(u16x4*)(xhi + (size_t)i * 4) = hi;
    *(u16x4*)(xlo + (size_t)i * 4) = lo;
}

// ---------------- transpose + split W[2] -> Wt (col-major K-contig) ----------------
__global__ __launch_bounds__(256) void prep_w(const float* __restrict__ W2,
                                              unsigned short* __restrict__ wthi,
                                              unsigned short* __restrict__ wtlo) {
    __shared__ float tile[64][65];
    int bc = blockIdx.x;      // output-col tile
    int bk = blockIdx.y;      // k tile
    int t = threadIdx.x;
    int tj = t & 63, ti = t >> 6;
#pragma unroll
    for (int u = 0; u < 16; ++u) {
        int r = u * 4 + ti;   // k-local
        tile[r][tj] = W2[(size_t)(bk * 64 + r) * DIM + bc * 64 + tj];
    }
    __syncthreads();
#pragma unroll
    for (int u = 0; u < 16; ++u) {
        int cr = u * 4 + ti;  // c-local
        float v = tile[tj][cr];   // = W2[bk*64+tj][bc*64+cr]
        unsigned short hb = f2bf_rne(v);
        float rres = v - bf2f(hb);
        size_t o = (size_t)(bc * 64 + cr) * DIM + bk * 64 + tj;
        wthi[o] = hb;
        wtlo[o] = f2bf_rne(rres);
    }
}

// ---------------- 3-term split-bf16 MFMA GEMM: h = x @ W2 (bf16 output) ----------------
// x @ W ~= xhi@Whi + xhi@Wlo + xlo@Whi  (fp32 accumulate)
//
// Round-6 lesson: global_load_lds + fragment-order LDS forces a SCATTERED
// global lane order (consecutive lanes 2048 B apart) -> TA coalescer issues
// ~4x L2 requests -> gemm3 82->128 us despite 0 bank conflicts.
// Fix: reg-staging. ds_write allows per-lane scatter, so we get all three:
//   (1) sorted-contiguous global loads: lane l -> row l>>2, 16B seg l&3
//       (lanes 0-3 = one 64 B line, fully ascending)
//   (2) fragment-order LDS via scatter write: byte (l>>2)*16 + (l&3)*256
//       -> bijection over each 1 KB subtile, every bank exactly 8 words,
//       ZERO write conflicts
//   (3) linear fragment reads at lane*16 -> ZERO read conflicts
// Plus T14 issue-early: next K-tile's global loads issue right after the
// ds_writes, hiding memory latency under the 48 MFMAs of the current tile.
#define BM 128
#define BN 128
#define BK 32
#define NROWT ((N_NODES + BM - 1) / BM)   // 79 row tiles
#define NCOLT (DIM / BN)                  // 8 col tiles

__global__ __launch_bounds__(256) void gemm3(const unsigned short* __restrict__ xhi,
                                             const unsigned short* __restrict__ xlo,
                                             const unsigned short* __restrict__ wthi,
                                             const unsigned short* __restrict__ wtlo,
                                             unsigned short* __restrict__ hb) {
    // XCD-grouping swizzle (round-robin id%8 -> XCD): the 8 col-tiles sharing
    // one A row-block run on ONE XCD -> A read once from HBM (FETCH 168->53 MB).
    const int id = blockIdx.x;
    const int xcd = id & 7;
    const int br = xcd + 8 * (id >> 6);     // row tile
    const int bc = (id >> 3) & 7;           // col tile
    if (br >= NROWT) return;
    const int r0 = br * BM;
    const int c0 = bc * BN;

    __shared__ short lds[4][BM * BK];   // 0:Ahi 1:Alo 2:Bhi 3:Blo — 8 KB each
    const int t = threadIdx.x;
    const int lane = t & 63, wid = t >> 6;
    const int wm = wid >> 1, wn = wid & 1;

    // each wave stages its own buffer: wave 0:Ahi 1:Alo 2:Bhi 3:Blo
    const unsigned short* const srcs[4] = {xhi, xlo, wthi, wtlo};
    const unsigned short* wbase = srcs[wid];
    const int rowb = (wid < 2) ? r0 : c0;
    // OOB A-rows (last row tile) read garbage inside ws (xlo/wthi regions);
    // those acc lanes are never stored (row<N_NODES guard).

    // sorted global source: lane l covers (row rowb + j*16 + (l>>2), seg l&3)
    const unsigned short* gsrc = wbase + (size_t)(rowb + (lane >> 2)) * DIM + (lane & 3) * 8;
    // LDS scatter-write offset (shorts): elem (r=l>>2, kslot=l&3) of subtile j
    // -> fragment lane r + kslot*16 -> short offset j*512 + (l>>2)*8 + (l&3)*128
    const int woff = (lane >> 2) * 8 + (lane & 3) * 128;

    f32x4 acc[4][4];
#pragma unroll
    for (int mi = 0; mi < 4; ++mi)
#pragma unroll
        for (int ni = 0; ni < 4; ++ni) acc[mi][ni] = (f32x4){0.f, 0.f, 0.f, 0.f};

    u16x8 stg[8];
#pragma unroll
    for (int j = 0; j < 8; ++j)
        stg[j] = *(const u16x8*)(gsrc + (size_t)(j * 16) * DIM);

    for (int k0 = 0; k0 < DIM; k0 += BK) {
        __syncthreads();   // previous iteration's fragment reads complete
#pragma unroll
        for (int j = 0; j < 8; ++j)
            *(u16x8*)&lds[wid][j * 512 + woff] = stg[j];
        __syncthreads();

        // T14 issue-early: next tile's loads in flight during this tile's MFMAs
        if (k0 + BK < DIM) {
            const unsigned short* g2 = gsrc + k0 + BK;
#pragma unroll
            for (int j = 0; j < 8; ++j)
                stg[j] = *(const u16x8*)(g2 + (size_t)(j * 16) * DIM);
        }

        bf16x8 ahi[4], alo[4], bhi[4], blo[4];
#pragma unroll
        for (int mi = 0; mi < 4; ++mi) {
            int sub = wm * 4 + mi;          // A subtile index (row>>4)
            ahi[mi] = *(const bf16x8*)&lds[0][sub * 512 + lane * 8];
            alo[mi] = *(const bf16x8*)&lds[1][sub * 512 + lane * 8];
        }
#pragma unroll
        for (int ni = 0; ni < 4; ++ni) {
            int sub = wn * 4 + ni;          // B subtile index
            bhi[ni] = *(const bf16x8*)&lds[2][sub * 512 + lane * 8];
            blo[ni] = *(const bf16x8*)&lds[3][sub * 512 + lane * 8];
        }
#pragma unroll
        for (int mi = 0; mi < 4; ++mi)
#pragma unroll
            for (int ni = 0; ni < 4; ++ni) {
                f32x4 c = acc[mi][ni];
                c = __builtin_amdgcn_mfma_f32_16x16x32_bf16(ahi[mi], bhi[ni], c, 0, 0, 0);
                c = __builtin_amdgcn_mfma_f32_16x16x32_bf16(ahi[mi], blo[ni], c, 0, 0, 0);
                c = __builtin_amdgcn_mfma_f32_16x16x32_bf16(alo[mi], bhi[ni], c, 0, 0, 0);
                acc[mi][ni] = c;
            }
    }

    // epilogue: bf16 store (C/D map: col=lane&15, row=(lane>>4)*4+v  [m89/m91])
#pragma unroll
    for (int mi = 0; mi < 4; ++mi)
#pragma unroll
        for (int ni = 0; ni < 4; ++ni)
#pragma unroll
            for (int v = 0; v < 4; ++v) {
                int row = r0 + wm * 64 + mi * 16 + ((lane >> 4) << 2) + v;
                if (row < N_NODES) {
                    int col = c0 + wn * 64 + ni * 16 + (lane & 15);
                    hb[(size_t)row * DIM + col] = f2bf_rne(acc[mi][ni][v]);
                }
            }
}

// ---------------- per-node attention logits es/ed (bf16 h, vectorized) ----------------
__global__ __launch_bounds__(256) void dots_k(const unsigned short* __restrict__ hb,
                                              const float* __restrict__ asrc,
                                              const float* __restrict__ adst,
                                              float* __restrict__ es,
                                              float* __restrict__ ed) {
    int wid = threadIdx.x >> 6, lane = threadIdx.x & 63;
    int n = blockIdx.x * 4 + wid;
    if (n >= N_NODES) return;
    // lane owns elements [lane*16, lane*16+16) -> all within head lane>>4
    const unsigned short* hr = hb + (size_t)n * DIM + lane * 16;
    u16x8 a = *(const u16x8*)hr;
    u16x8 b8 = *(const u16x8*)(hr + 8);
    const float* ap = asrc + lane * 16;
    const float* dp = adst + lane * 16;
    float sa = 0.f, sd = 0.f;
#pragma unroll
    for (int j = 0; j < 8; ++j) {
        float v = bf2f(a[j]);
        sa += v * ap[j];
        sd += v * dp[j];
    }
#pragma unroll
    for (int j = 0; j < 8; ++j) {
        float v = bf2f(b8[j]);
        sa += v * ap[8 + j];
        sd += v * dp[8 + j];
    }
#pragma unroll
    for (int d = 1; d < 16; d <<= 1) {
        sa += __shfl_xor(sa, d);
        sd += __shfl_xor(sd, d);
    }
    if ((lane & 15) == 0) {
        int head = lane >> 4;
        es[(size_t)n * 4 + head] = sa;
        ed[(size_t)n * 4 + head] = sd;
    }
}

// ---------------- per-graph init ----------------
__global__ void init_misc(int* gcnt, int* gbeg, int* gend) {
    int t = threadIdx.x;
    if (t < NGRAPH) { gcnt[t] = 0; gbeg[t] = 0x7fffffff; gend[t] = -1; }
}

// ---------------- CSR build ----------------
__global__ void init_counts(const int* __restrict__ batch, int* cnt, int* cursor,
                            int* gcnt, int* gbeg, int* gend) {
    int n = blockIdx.x * 256 + threadIdx.x;
    if (n >= N_NODES) return;
    cnt[n] = 1;          // self loop
    cursor[n] = 0;
    int b = batch[n];
    atomicAdd(gcnt + b, 1);
    atomicMin(gbeg + b, n);
    atomicMax(gend + b, n);
}

__global__ void edge_hist(const int* __restrict__ dst, int* cnt) {
    int e = blockIdx.x * 256 + threadIdx.x;
    if (e >= N_EDGES) return;
    atomicAdd(cnt + dst[e], 1);
}

// shfl-based scan (wave-level, few barriers)
__global__ __launch_bounds__(1024) void scan_k(const int* __restrict__ cnt, int* __restrict__ off) {
    __shared__ int wsh[16];
    __shared__ int tot_s;
    int t = threadIdx.x, lane = t & 63, wv = t >> 6;
    int running = 0;
    for (int c0 = 0; c0 < N_NODES; c0 += 1024) {
        int i = c0 + t;
        int v = (i < N_NODES) ? cnt[i] : 0;
        int s = v;
#pragma unroll
        for (int d = 1; d < 64; d <<= 1) {
            int y = __shfl_up(s, d);
            if (lane >= d) s += y;
        }
        if (lane == 63) wsh[wv] = s;
        __syncthreads();
        if (wv == 0) {
            int wsv = (lane < 16) ? wsh[lane] : 0;
            int e = wsv;
#pragma unroll
            for (int d = 1; d < 16; d <<= 1) {
                int y = __shfl_up(e, d);
                if (lane >= d) e += y;
            }
            if (lane < 16) wsh[lane] = e - wsv;   // exclusive wave prefix
            if (lane == 15) tot_s = e;            // chunk total
        }
        __syncthreads();
        if (i < N_NODES) off[i] = running + wsh[wv] + s - v;
        running += tot_s;
    }
}

__global__ void bucket_k(const int* __restrict__ src, const int* __restrict__ dst,
                         const int* __restrict__ off, int* cursor, int* bucket) {
    int e = blockIdx.x * 256 + threadIdx.x;
    if (e >= ETOT) return;
    int d = (e < N_EDGES) ? dst[e] : (e - N_EDGES);
    int pos = atomicAdd(cursor + d, 1);
    bucket[off[d] + pos] = e;
}

// ---------------- fused softmax + aggregate + bias + relu -> out[n] ----------------
#define HCAP 192
__global__ __launch_bounds__(256) void aggregate_k(const unsigned short* __restrict__ hb,
                                                   const float* __restrict__ es,
                                                   const float* __restrict__ ed,
                                                   const int* __restrict__ src,
                                                   const int* __restrict__ cnt,
                                                   const int* __restrict__ off,
                                                   const int* __restrict__ bucket,
                                                   const float* __restrict__ b2,
                                                   float* __restrict__ out) {
    int n = blockIdx.x, t = threadIdx.x;
    int deg = cnt[n], base = off[n];
    f32x4 edn = *(const f32x4*)(ed + (size_t)n * 4);
    __shared__ int  s_src[HCAP];
    __shared__ f32x4 s_e[HCAP];
    __shared__ f32x4 wred[4];

    // phase 1: edge scores + per-head max
    f32x4 m4 = {-3e38f, -3e38f, -3e38f, -3e38f};
    for (int i = t; i < deg; i += 256) {
        int eid = bucket[base + i];
        int s = (eid < N_EDGES) ? src[eid] : (eid - N_EDGES);
        f32x4 e4 = *(const f32x4*)(es + (size_t)s * 4);
        e4.x = lrelu(e4.x + edn.x); e4.y = lrelu(e4.y + edn.y);
        e4.z = lrelu(e4.z + edn.z); e4.w = lrelu(e4.w + edn.w);
        if (i < HCAP) { s_src[i] = s; s_e[i] = e4; }
        m4.x = fmaxf(m4.x, e4.x); m4.y = fmaxf(m4.y, e4.y);
        m4.z = fmaxf(m4.z, e4.z); m4.w = fmaxf(m4.w, e4.w);
    }
#pragma unroll
    for (int d = 1; d < 64; d <<= 1) {
        m4.x = fmaxf(m4.x, __shfl_xor(m4.x, d));
        m4.y = fmaxf(m4.y, __shfl_xor(m4.y, d));
        m4.z = fmaxf(m4.z, __shfl_xor(m4.z, d));
        m4.w = fmaxf(m4.w, __shfl_xor(m4.w, d));
    }
    if ((t & 63) == 0) wred[t >> 6] = m4;
    __syncthreads();
    f32x4 mm = wred[0];
#pragma unroll
    for (int w = 1; w < 4; ++w) {
        mm.x = fmaxf(mm.x, wred[w].x); mm.y = fmaxf(mm.y, wred[w].y);
        mm.z = fmaxf(mm.z, wred[w].z); mm.w = fmaxf(mm.w, wred[w].w);
    }
    int hd = t >> 6;
    float mh = hd == 0 ? mm.x : hd == 1 ? mm.y : hd == 2 ? mm.z : mm.w;

    // phase 2: weighted accumulate over bf16 h rows (thread t owns cols [t*4, t*4+4))
    f32x4 acc = {0.f, 0.f, 0.f, 0.f};
    float sump = 0.f;
    for (int i = 0; i < deg; ++i) {
        int s;
        f32x4 e4;
        if (i < HCAP) { s = s_src[i]; e4 = s_e[i]; }
        else {
            int eid = bucket[base + i];
            s = (eid < N_EDGES) ? src[eid] : (eid - N_EDGES);
            e4 = *(const f32x4*)(es + (size_t)s * 4);
            e4.x = lrelu(e4.x + edn.x); e4.y = lrelu(e4.y + edn.y);
            e4.z = lrelu(e4.z + edn.z); e4.w = lrelu(e4.w + edn.w);
        }
        float eh = hd == 0 ? e4.x : hd == 1 ? e4.y : hd == 2 ? e4.z : e4.w;
        float p = expf(eh - mh);
        sump += p;
        u16x4 q = *(const u16x4*)(hb + (size_t)s * DIM + t * 4);
        f32x4 hv = {bf2f(q[0]), bf2f(q[1]), bf2f(q[2]), bf2f(q[3])};
        acc += p * hv;
    }
    float inv = 1.0f / (sump + 1e-16f);
    f32x4 bb = *(const f32x4*)(b2 + t * 4);
    f32x4 r = acc * inv + bb;
    r.x = fmaxf(r.x, 0.f); r.y = fmaxf(r.y, 0.f);
    r.z = fmaxf(r.z, 0.f); r.w = fmaxf(r.w, 0.f);
    *(f32x4*)(out + (size_t)n * DIM + t * 4) = r;   // plain coalesced store, no atomics
}

// ---------------- per-graph pooling (no atomics: batch is sorted) ----------------
__global__ __launch_bounds__(256) void pool_k(const float* __restrict__ out,
                                              const int* __restrict__ gbeg,
                                              const int* __restrict__ gend,
                                              float* __restrict__ pooled) {
    int g = blockIdx.x, c = blockIdx.y, t = threadIdx.x;
    int col = c * 256 + t;
    int b0 = gbeg[g], b1 = gend[g];
    float acc = 0.f;
    for (int n = b0; n <= b1; ++n) acc += out[(size_t)n * DIM + col];
    pooled[(size_t)g * DIM + col] = acc;   // sum; final_k divides by count
}

// ---------------- final: (pooled/cnt) @ Wr + br ----------------
__global__ __launch_bounds__(256) void final_k(const float* __restrict__ pooled,
                                               const int* __restrict__ gcnt,
                                               const float* __restrict__ Wr,
                                               const float* __restrict__ br,
                                               float* __restrict__ out) {
    int g = blockIdx.x, t = threadIdx.x;
    float s0 = 0.f, s1 = 0.f;
    for (int d = t; d < DIM; d += 256) {
        float v = pooled[(size_t)g * DIM + d];
        s0 += v * Wr[d * 2];
        s1 += v * Wr[d * 2 + 1];
    }
    __shared__ float r0[256], r1[256];
    r0[t] = s0; r1[t] = s1;
    __syncthreads();
    for (int st = 128; st > 0; st >>= 1) {
        if (t < st) { r0[t] += r0[t + st]; r1[t] += r1[t + st]; }
        __syncthreads();
    }
    if (t == 0) {
        float c = fmaxf((float)gcnt[g], 1.f);
        out[g * 2 + 0] = r0[0] / c + br[0];
        out[g * 2 + 1] = r1[0] / c + br[1];
    }
}

// ---------------- launch ----------------
extern "C" void kernel_launch(void* const* d_in, const int* in_sizes, int n_in,
                              void* d_out, int out_size, void* d_ws, size_t ws_size,
                              hipStream_t stream) {
    (void)in_sizes; (void)n_in; (void)out_size; (void)ws_size;
    const float* x     = (const float*)d_in[0];
    const int*   ei    = (const int*)d_in[1];
    const int*   batch = (const int*)d_in[2];
    const float* W     = (const float*)d_in[3];
    const float* a_src = (const float*)d_in[4];
    const float* a_dst = (const float*)d_in[5];
    const float* b     = (const float*)d_in[6];
    const float* Wr    = (const float*)d_in[7];
    const float* br    = (const float*)d_in[8];

    // Reference: each block reads the ORIGINAL x -> only block i=2 matters.
    const float* W2    = W + (size_t)2 * DIM * DIM;
    const float* asrc2 = a_src + 2 * NHEAD * DHEAD;
    const float* adst2 = a_dst + 2 * NHEAD * DHEAD;
    const float* b2    = b + 2 * DIM;
    const int* srcI = ei;
    const int* dstI = ei + N_EDGES;

    char* wsp = (char*)d_ws;
    size_t o = 0;
    auto alloc = [&](size_t bytes) -> char* {
        char* p = wsp + o;
        o = (o + bytes + 255) & ~(size_t)255;
        return p;
    };
    unsigned short* xhi  = (unsigned short*)alloc((size_t)N_NODES * DIM * 2);  // 20.48 MB
    unsigned short* xlo  = (unsigned short*)alloc((size_t)N_NODES * DIM * 2);  // 20.48 MB (contiguous after xhi)
    unsigned short* wthi = (unsigned short*)alloc((size_t)DIM * DIM * 2);
    unsigned short* wtlo = (unsigned short*)alloc((size_t)DIM * DIM * 2);
    unsigned short* hb   = (unsigned short*)alloc((size_t)N_NODES * DIM * 2);  // h in bf16
    float* es   = (float*)alloc((size_t)N_NODES * 4 * 4);
    float* ed   = (float*)alloc((size_t)N_NODES * 4 * 4);
    int*   cnt  = (int*)alloc((size_t)N_NODES * 4);
    int*   offs = (int*)alloc((size_t)N_NODES * 4);
    int*   curs = (int*)alloc((size_t)N_NODES * 4);
    int*   bkt  = (int*)alloc((size_t)ETOT * 4);
    float* pooled = (float*)alloc((size_t)NGRAPH * DIM * 4);
    int*   gcnt   = (int*)alloc(NGRAPH * 4);
    int*   gbeg   = (int*)alloc(NGRAPH * 4);
    int*   gend   = (int*)alloc(NGRAPH * 4);
    // out[n] (41 MB f32) aliases xhi+xlo — dead after gemm3. (xhi size is a
    // multiple of 256 so xlo is contiguous; combined = exactly N*DIM*4 bytes.)
    float* outn = (float*)xhi;

    init_misc<<<1, 64, 0, stream>>>(gcnt, gbeg, gend);
    prep_x<<<(N_NODES * DIM / 4 + 255) / 256, 256, 0, stream>>>(x, xhi, xlo);
    prep_w<<<dim3(16, 16), 256, 0, stream>>>(W2, wthi, wtlo);
    gemm3<<<((NROWT + 7) / 8) * 8 * NCOLT, 256, 0, stream>>>(xhi, xlo, wthi, wtlo, hb);
    dots_k<<<(N_NODES + 3) / 4, 256, 0, stream>>>(hb, asrc2, adst2, es, ed);

    init_counts<<<(N_NODES + 255) / 256, 256, 0, stream>>>(batch, cnt, curs, gcnt, gbeg, gend);
    edge_hist<<<(N_EDGES + 255) / 256, 256, 0, stream>>>(dstI, cnt);
    scan_k<<<1, 1024, 0, stream>>>(cnt, offs);
    bucket_k<<<(ETOT + 255) / 256, 256, 0, stream>>>(srcI, dstI, offs, curs, bkt);

    aggregate_k<<<N_NODES, 256, 0, stream>>>(hb, es, ed, srcI, cnt, offs, bkt, b2, outn);
    pool_k<<<dim3(NGRAPH, 4), 256, 0, stream>>>(outn, gbeg, gend, pooled);
    final_k<<<NGRAPH, 256, 0, stream>>>(pooled, gcnt, Wr, br, (float*)d_out);
}